// Round 6
// baseline (96.379 us; speedup 1.0000x reference)
//
#include <hip/hip_runtime.h>

#define NB 8
#define NQ 4096   // h*w
#define NP 2048
#define FINF 3.402823466e38f

typedef float f2 __attribute__((ext_vector_type(2)));
typedef float f4 __attribute__((ext_vector_type(4)));

// Packed fma: all operands are 64-bit pairs (VOP3P requirement — scalar src0 does
// NOT assemble; broadcast must be materialized in the pair).
__device__ __forceinline__ f2 pk_fma(f2 a, f2 b, f2 c) {
    f2 d;
    asm("v_pk_fma_f32 %0, %1, %2, %3" : "=v"(d) : "v"(a), "v"(b), "v"(c));
    return d;
}
__device__ __forceinline__ float min3f(float a, float b, float c) {
    float d;
    asm("v_min3_f32 %0, %1, %2, %3" : "=v"(d) : "v"(a), "v"(b), "v"(c));
    return d;
}

// Single fused kernel: 1024 blocks x 256 threads, 34 KB LDS, <=128 VGPR
// -> 4 blocks/CU (16 waves/CU), ALL blocks co-resident.
//  blocks [0,512):    bp. blk=(b*32+pt)*2+half: owns 64 p, stages one y-half (1024 pairs).
//                     Output: 64 partial row-mins (+owned norm) -> ws[blk*64..].
//  blocks [512,1024): bq. idx=blk-512, b=idx>>6, qt=idx&63: owns 64 q, stages all 2048 t.
//                     Output: complete mins summed -> ws[32768+idx].
// Inner shape (both paths): pg=tid&3 owns 16 points (f2 broadcast pairs in regs),
// s=tid>>2 is the slice; pair index j*64+s -> ds_read_b128 imm offsets, conflict-free.
// Per 2 distances: 3 v_pk_fma_f32 + 1 v_min3_f32.
// Finish: threadfence + done-counter; last block reduces all partials deterministically.
__global__ __launch_bounds__(256, 4) void chamfer_fused(const float* __restrict__ y,
                                                        const float* __restrict__ t,
                                                        const float* __restrict__ w,
                                                        float* __restrict__ ws,
                                                        int* __restrict__ cnt,
                                                        float* __restrict__ out)
{
    __shared__ f4 lds4[2048 + 64 + 64];   // A[1024] | B[1024] | quad[64] | scrB(256 f)
    __shared__ int lastFlag;
    __shared__ double redd[4];
    f4* ldsA = lds4;
    f4* ldsB = lds4 + 1024;
    f4* quad = lds4 + 2048;
    float* scr  = (float*)lds4;                 // 64*65 floats (aliases A+B after compute)
    float* scrB = (float*)(lds4 + 2048 + 64);   // 256 floats

    const int tid = threadIdx.x;
    const int blk = blockIdx.x;
    const int pg  = tid & 3;
    const int s   = tid >> 2;
    const float w0 = w[0]*w[0], w1 = w[1]*w[1], w2 = w[2]*w[2];
    const bool isBQ = blk >= 512;

    if (!isBQ) {
        // ---- bp: own 64 p, stage one y-half (1024 pairs = 2048 q-points) ----
        const int b = blk >> 6, pt = (blk >> 1) & 31, half = blk & 1;
        const float* yb = y + (size_t)b * 3 * NQ + half * 2048;
        const f2* xs = (const f2*)yb;
        const f2* ys = (const f2*)(yb + NQ);
        const f2* zs = (const f2*)(yb + 2*NQ);
        for (int i = tid; i < 1024; i += 256) {
            const f2 xp = xs[i], yp = ys[i], zp = zs[i];
            const float n0 = w0*xp.x*xp.x + w1*yp.x*yp.x + w2*zp.x*zp.x;
            const float n1 = w0*xp.y*xp.y + w1*yp.y*yp.y + w2*zp.y*zp.y;
            f4 va = {xp.x, xp.y, yp.x, yp.y};
            f4 vb = {zp.x, zp.y, n0, n1};
            ldsA[i] = va; ldsB[i] = vb;
        }
        if (tid < 64) {
            const float* tp = t + ((size_t)b * NP + pt*64 + tid) * 3;
            const float t0 = tp[0], t1 = tp[1], t2 = tp[2];
            f4 q = {-2.f*w0*t0, -2.f*w1*t1, -2.f*w2*t2,
                    w0*t0*t0 + w1*t1*t1 + w2*t2*t2};
            quad[tid] = q;
        }
    } else {
        // ---- bq: own 64 q, stage all 2048 t-points (1024 pairs) ----
        const int idx = blk - 512;
        const int b = idx >> 6, qt = idx & 63;
        const float* tb = t + (size_t)b * NP * 3;
        for (int i = tid; i < 1024; i += 256) {
            const f2* tp2 = (const f2*)(tb + i*6);
            const f2 u0 = tp2[0], u1 = tp2[1], u2 = tp2[2];
            // pt0=(u0.x,u0.y,u1.x)  pt1=(u1.y,u2.x,u2.y)
            const float n0 = w0*u0.x*u0.x + w1*u0.y*u0.y + w2*u1.x*u1.x;
            const float n1 = w0*u1.y*u1.y + w1*u2.x*u2.x + w2*u2.y*u2.y;
            f4 va = {u0.x, u1.y, u0.y, u2.x};
            f4 vb = {u1.x, u2.y, n0, n1};
            ldsA[i] = va; ldsB[i] = vb;
        }
        if (tid < 64) {
            const float* yb = y + (size_t)b * 3 * NQ;
            const int q = qt*64 + tid;
            const float y0 = yb[q], y1 = yb[NQ+q], y2 = yb[2*NQ+q];
            f4 qv = {-2.f*w0*y0, -2.f*w1*y1, -2.f*w2*y2,
                     w0*y0*y0 + w1*y1*y1 + w2*y2*y2};
            quad[tid] = qv;
        }
    }
    __syncthreads();

    // owned points as f2 broadcast pairs (loop-invariant, materialized once)
    f2 qx[16], qy[16], qz[16];
    float mm[16];
    #pragma unroll
    for (int r = 0; r < 16; ++r) {
        const f4 qv = quad[pg*16 + r];
        f2 bx = {qv.x, qv.x}; qx[r] = bx;
        f2 by = {qv.y, qv.y}; qy[r] = by;
        f2 bz = {qv.z, qv.z}; qz[r] = bz;
        mm[r] = FINF;
    }

    const f4* Ap = ldsA + s;
    const f4* Bp = ldsB + s;
    #pragma unroll 2
    for (int j = 0; j < 16; ++j) {
        const f4 a  = Ap[j * 64];          // imm offset j*1024B
        const f4 bb = Bp[j * 64];
        const f2 vx = a.xy,  vy = a.zw;
        const f2 vz = bb.xy, vn = bb.zw;
        #pragma unroll
        for (int r = 0; r < 16; ++r) {
            f2 acc = pk_fma(qx[r], vx, vn);
            acc = pk_fma(qy[r], vy, acc);
            acc = pk_fma(qz[r], vz, acc);
            mm[r] = min3f(mm[r], acc.x, acc.y);
        }
    }
    __syncthreads();   // ldsA/ldsB reads done -> reuse as scratch

    // scr[j_own][s], stride 65 (2-way aliasing only)
    #pragma unroll
    for (int r = 0; r < 16; ++r) scr[(pg*16 + r)*65 + s] = mm[r];
    __syncthreads();

    // fold 64 slices -> 4 group-partials per owned point
    {
        const int j = tid & 63, g = tid >> 6;
        float v = FINF;
        #pragma unroll
        for (int k = 0; k < 16; ++k) v = fminf(v, scr[j*65 + g*16 + k]);
        scrB[g*64 + j] = v;
    }
    __syncthreads();

    if (tid < 64) {
        float v = fminf(fminf(scrB[tid], scrB[64+tid]),
                        fminf(scrB[128+tid], scrB[192+tid]))
                + quad[tid].w;             // deferred owned norm
        if (!isBQ) {
            ws[blk*64 + tid] = v;          // partial row-min (one y-half)
        } else {
            for (int off = 32; off > 0; off >>= 1) v += __shfl_down(v, off);
            if (tid == 0) ws[32768 + (blk - 512)] = v;   // complete, summed
        }
    }

    // ---- last-block deterministic reduction ----
    __threadfence();                       // release our partials (all threads)
    __syncthreads();
    if (tid == 0) lastFlag = (atomicAdd(cnt, 1) == (int)gridDim.x - 1);
    __syncthreads();
    if (!lastFlag) return;
    __threadfence();                       // acquire everyone's partials

    double sbp = 0.0, sbq = 0.0;
    for (int i = tid; i < 16384; i += 256) {        // bt in [0,256), j in [0,64)
        const int bt = i >> 6, j = i & 63;
        sbp += (double)fminf(ws[bt*128 + j], ws[bt*128 + 64 + j]);
    }
    for (int i = tid; i < 512; i += 256)
        sbq += (double)ws[32768 + i];
    double sv = sbp * (1.0 / (NB * NP)) + sbq * (1.0 / (NB * NQ));

    for (int off = 32; off > 0; off >>= 1) sv += __shfl_down(sv, off);
    if ((tid & 63) == 0) redd[tid >> 6] = sv;
    __syncthreads();
    if (tid == 0) out[0] = (float)(redd[0] + redd[1] + redd[2] + redd[3]);
}

extern "C" void kernel_launch(void* const* d_in, const int* in_sizes, int n_in,
                              void* d_out, int out_size, void* d_ws, size_t ws_size,
                              hipStream_t stream) {
    const float* y = (const float*)d_in[0];   // [8,3,64,64]
    const float* t = (const float*)d_in[1];   // [8,2048,3]
    const float* w = (const float*)d_in[2];   // [3]
    float* out = (float*)d_out;
    float* ws  = (float*)d_ws;                // [0,32768) bp partials | [32768,33280) bq sums
    int*   cnt = (int*)(ws + 33280);          // done-counter

    hipMemsetAsync(cnt, 0, sizeof(int), stream);
    chamfer_fused<<<1024, 256, 0, stream>>>(y, t, w, ws, cnt, out);
}

// Round 7
// 23.899 us; speedup vs baseline: 4.0328x; 4.0328x over previous
//
#include <hip/hip_runtime.h>

#define NB 8
#define NQ 4096   // h*w
#define NP 2048
#define FINF 3.402823466e38f

typedef float f2 __attribute__((ext_vector_type(2)));
typedef float f4 __attribute__((ext_vector_type(4)));

// VOP3P packed FMA. ALL operands must be register pairs (R5 lesson: scalar src0
// does not assemble). Broadcast of one half of src0 is done via op_sel/op_sel_hi.
// d = {a.lo*b.lo+c.lo, a.lo*b.hi+c.hi}   (broadcast src0 LO half)
__device__ __forceinline__ f2 pk_fma_lo(f2 a, f2 b, f2 c) {
    f2 d;
    asm("v_pk_fma_f32 %0, %1, %2, %3 op_sel_hi:[0,1,1]"
        : "=v"(d) : "v"(a), "v"(b), "v"(c));
    return d;
}
// d = {a.hi*b.lo+c.lo, a.hi*b.hi+c.hi}   (broadcast src0 HI half)
__device__ __forceinline__ f2 pk_fma_hi(f2 a, f2 b, f2 c) {
    f2 d;
    asm("v_pk_fma_f32 %0, %1, %2, %3 op_sel:[1,0,0] op_sel_hi:[1,1,1]"
        : "=v"(d) : "v"(a), "v"(b), "v"(c));
    return d;
}
__device__ __forceinline__ float min3f(float a, float b, float c) {
    float d;
    asm("v_min3_f32 %0, %1, %2, %3" : "=v"(d) : "v"(a), "v"(b), "v"(c));
    return d;
}

// Main: 1024 blocks x 256 threads, 34 KB LDS, ~90 VGPR (cap 128 via bounds) ->
// 4 blocks/CU, 16 waves/CU, all blocks co-resident.
//  blocks [0,512):    bp. blk=(b*32+pt)*2+half: owns 64 p, stages one y-half (1024 pairs).
//                     Output: 64 partial row-mins (+owned norm) -> ws[blk*64..].
//  blocks [512,1024): bq. idx=blk-512, b=idx>>6, qt=idx&63: owns 64 q, stages all 2048 t
//                     (1024 pairs). Output: complete mins summed -> ws[32768+idx].
// Thread split: pg = tid>>6 (wave id) -> wave owns 16 points; quad[] reads are
// wave-uniform (LDS broadcast, conflict-free). s = tid&63 -> inner ds_read_b128 is
// stride-1 across the wave (free 2-way). Owned-point registers are PACKED:
// qxy[r]={x,y} (pair), qz2[r>>1]={z_even,z_odd} (pair shared by 2 points) = 48 VGPR,
// consumed via op_sel half-broadcast. Per 2 distances: 3 pk_fma + 1 min3.
__global__ __launch_bounds__(256, 4) void chamfer_main(const float* __restrict__ y,
                                                       const float* __restrict__ t,
                                                       const float* __restrict__ w,
                                                       float* __restrict__ ws)
{
    __shared__ f4 lds4[2048 + 64 + 64];   // A[1024] | B[1024] | quad[64] | scrB(256 f)
    f4* ldsA = lds4;
    f4* ldsB = lds4 + 1024;
    f4* quad = lds4 + 2048;
    float* scr  = (float*)lds4;                 // 64*65 floats, aliases A+B after compute
    float* scrB = (float*)(lds4 + 2048 + 64);   // 256 floats

    const int tid = threadIdx.x;
    const int blk = blockIdx.x;
    const int pg  = tid >> 6;    // wave id: owned group (wave-uniform)
    const int s   = tid & 63;    // slice/lane
    const float w0 = w[0]*w[0], w1 = w[1]*w[1], w2 = w[2]*w[2];
    const bool isBQ = blk >= 512;

    if (!isBQ) {
        // ---- bp: own 64 p, stage one y-half (1024 pairs = 2048 q-points) ----
        const int b = blk >> 6, pt = (blk >> 1) & 31, half = blk & 1;
        const float* yb = y + (size_t)b * 3 * NQ + half * 2048;
        const f2* xs = (const f2*)yb;
        const f2* ys = (const f2*)(yb + NQ);
        const f2* zs = (const f2*)(yb + 2*NQ);
        for (int i = tid; i < 1024; i += 256) {
            const f2 xp = xs[i], yp = ys[i], zp = zs[i];
            const float n0 = w0*xp.x*xp.x + w1*yp.x*yp.x + w2*zp.x*zp.x;
            const float n1 = w0*xp.y*xp.y + w1*yp.y*yp.y + w2*zp.y*zp.y;
            f4 va = {xp.x, xp.y, yp.x, yp.y};
            f4 vb = {zp.x, zp.y, n0, n1};
            ldsA[i] = va; ldsB[i] = vb;
        }
        if (tid < 64) {
            const float* tp = t + ((size_t)b * NP + pt*64 + tid) * 3;
            const float t0 = tp[0], t1 = tp[1], t2 = tp[2];
            f4 q = {t0, t1, t2, w0*t0*t0 + w1*t1*t1 + w2*t2*t2};
            quad[tid] = q;
        }
    } else {
        // ---- bq: own 64 q, stage all 2048 t-points (1024 pairs) ----
        const int idx = blk - 512;
        const int b = idx >> 6, qt = idx & 63;
        const float* tb = t + (size_t)b * NP * 3;
        for (int i = tid; i < 1024; i += 256) {
            const f2* tp2 = (const f2*)(tb + i*6);
            const f2 u0 = tp2[0], u1 = tp2[1], u2 = tp2[2];
            // pt0=(u0.x,u0.y,u1.x)  pt1=(u1.y,u2.x,u2.y)
            const float n0 = w0*u0.x*u0.x + w1*u0.y*u0.y + w2*u1.x*u1.x;
            const float n1 = w0*u1.y*u1.y + w1*u2.x*u2.x + w2*u2.y*u2.y;
            f4 va = {u0.x, u1.y, u0.y, u2.x};
            f4 vb = {u1.x, u2.y, n0, n1};
            ldsA[i] = va; ldsB[i] = vb;
        }
        if (tid < 64) {
            const float* yb = y + (size_t)b * 3 * NQ;
            const int q = qt*64 + tid;
            const float y0 = yb[q], y1 = yb[NQ+q], y2 = yb[2*NQ+q];
            f4 qv = {y0, y1, y2, w0*y0*y0 + w1*y1*y1 + w2*y2*y2};
            quad[tid] = qv;
        }
    }
    __syncthreads();

    // Owned points, packed: per point one {-2w2x,-2w2y} pair + half of a z-pair.
    f2 qxy[16], qz2[8];
    float mm[16];
    #pragma unroll
    for (int r = 0; r < 16; ++r) {
        const f4 qv = quad[pg*16 + r];                    // wave-uniform -> broadcast
        f2 xy = { -2.f*w0*qv.x, -2.f*w1*qv.y };
        qxy[r] = xy;
        if ((r & 1) == 0) qz2[r >> 1].x = -2.f*w2*qv.z;
        else              qz2[r >> 1].y = -2.f*w2*qv.z;
        mm[r] = FINF;
    }

    const f4* Ap = ldsA + s;
    const f4* Bp = ldsB + s;
    #pragma unroll 2
    for (int j = 0; j < 16; ++j) {
        const f4 a  = Ap[j * 64];          // stride-1 across wave, imm offset j*1024B
        const f4 bb = Bp[j * 64];
        const f2 vx = a.xy,  vy = a.zw;
        const f2 vz = bb.xy, vn = bb.zw;
        #pragma unroll
        for (int h = 0; h < 8; ++h) {
            f2 acc0 = pk_fma_lo(qxy[2*h],   vx, vn);      // x0*vx + n
            acc0    = pk_fma_hi(qxy[2*h],   vy, acc0);    // + y0*vy
            acc0    = pk_fma_lo(qz2[h],     vz, acc0);    // + z0*vz
            mm[2*h] = min3f(mm[2*h], acc0.x, acc0.y);
            f2 acc1 = pk_fma_lo(qxy[2*h+1], vx, vn);
            acc1    = pk_fma_hi(qxy[2*h+1], vy, acc1);
            acc1    = pk_fma_hi(qz2[h],     vz, acc1);
            mm[2*h+1] = min3f(mm[2*h+1], acc1.x, acc1.y);
        }
    }
    __syncthreads();   // ldsA/ldsB reads done -> reuse as scratch

    // scr[j_own][s], stride 65: lane-consecutive writes, conflict-free
    #pragma unroll
    for (int r = 0; r < 16; ++r) scr[(pg*16 + r)*65 + s] = mm[r];
    __syncthreads();

    // fold 64 slices -> 4 group-partials per owned point
    {
        const int j = tid & 63, g = tid >> 6;
        float v = FINF;
        #pragma unroll
        for (int k = 0; k < 16; ++k) v = fminf(v, scr[j*65 + g*16 + k]);
        scrB[g*64 + j] = v;
    }
    __syncthreads();

    if (tid < 64) {
        const f4 qv = quad[tid];
        float v = fminf(fminf(scrB[tid], scrB[64+tid]),
                        fminf(scrB[128+tid], scrB[192+tid]))
                + qv.w;                    // deferred owned norm
        if (!isBQ) {
            ws[blk*64 + tid] = v;          // partial row-min (one y-half)
        } else {
            for (int off = 32; off > 0; off >>= 1) v += __shfl_down(v, off);
            if (tid == 0) ws[32768 + (blk - 512)] = v;   // complete, summed
        }
    }
}

// Single-block deterministic finish: merge bp halves, two means, scalar out.
__global__ __launch_bounds__(1024) void chamfer_reduce(const float* __restrict__ ws,
                                                       float* __restrict__ out)
{
    const int tid = threadIdx.x;
    double sbp = 0.0, sbq = 0.0;
    for (int i = tid; i < 16384; i += 1024) {      // bt = b*32+pt in [0,256), j in [0,64)
        const int bt = i >> 6, j = i & 63;
        sbp += (double)fminf(ws[bt*128 + j], ws[bt*128 + 64 + j]);
    }
    if (tid < 512) sbq = (double)ws[32768 + tid];
    double sv = sbp * (1.0 / (NB * NP)) + sbq * (1.0 / (NB * NQ));

    for (int off = 32; off > 0; off >>= 1) sv += __shfl_down(sv, off);

    __shared__ double redd[16];
    if ((tid & 63) == 0) redd[tid >> 6] = sv;
    __syncthreads();
    if (tid == 0) {
        double tot = 0.0;
        #pragma unroll
        for (int i = 0; i < 16; ++i) tot += redd[i];
        out[0] = (float)tot;
    }
}

extern "C" void kernel_launch(void* const* d_in, const int* in_sizes, int n_in,
                              void* d_out, int out_size, void* d_ws, size_t ws_size,
                              hipStream_t stream) {
    const float* y = (const float*)d_in[0];   // [8,3,64,64]
    const float* t = (const float*)d_in[1];   // [8,2048,3]
    const float* w = (const float*)d_in[2];   // [3]
    float* out = (float*)d_out;
    float* ws  = (float*)d_ws;                // [0,32768) bp partials | [32768,33280) bq sums

    chamfer_main<<<1024, 256, 0, stream>>>(y, t, w, ws);
    chamfer_reduce<<<1, 1024, 0, stream>>>(ws, out);
}